// Round 9
// baseline (99.666 us; speedup 1.0000x reference)
//
#include <hip/hip_runtime.h>
#include <hip/hip_bf16.h>

// ---------- types ----------
typedef short bf16x8 __attribute__((ext_vector_type(8)));   // 8 bf16 = 4 VGPR
typedef float f32x4 __attribute__((ext_vector_type(4)));
typedef unsigned short ushort_t;

#define SQ 2048
#define DIM 1024
#define NH 16
#define HD 64

__device__ __forceinline__ ushort_t f2bf(float f) {
    __hip_bfloat16 h = __float2bfloat16(f);     // HW v_cvt, RNE
    return *reinterpret_cast<ushort_t*>(&h);
}

__device__ __forceinline__ void load_lds16(const void* g, void* l) {
    __builtin_amdgcn_global_load_lds(
        (const __attribute__((address_space(1))) unsigned int*)g,
        (__attribute__((address_space(3))) unsigned int*)l, 16, 0, 0);
}

// ---------- kernel 1: fp32 -> bf16 (vectorized) ----------
__global__ void cvt_x(const float* __restrict__ in, ushort_t* __restrict__ out, int n4) {
    int i = blockIdx.x * blockDim.x + threadIdx.x;
    int stride = gridDim.x * blockDim.x;
    for (; i < n4; i += stride) {
        float4 f = reinterpret_cast<const float4*>(in)[i];
        ushort4 o;
        o.x = f2bf(f.x); o.y = f2bf(f.y); o.z = f2bf(f.z); o.w = f2bf(f.w);
        reinterpret_cast<ushort4*>(out)[i] = o;
    }
}

// ---------- kernel 2: transpose + convert: in[R][C] fp32 -> out[C][R] bf16 ----------
__global__ void transpose_cvt(const float* __restrict__ in, ushort_t* __restrict__ out,
                              int R, int C) {
    __shared__ ushort_t tile[32][33];
    int c0 = blockIdx.x * 32, r0 = blockIdx.y * 32;
    int tx = threadIdx.x, ty = threadIdx.y;     // block (32,8)
#pragma unroll
    for (int i = 0; i < 32; i += 8)
        tile[ty + i][tx] = f2bf(in[(size_t)(r0 + ty + i) * C + c0 + tx]);
    __syncthreads();
#pragma unroll
    for (int i = 0; i < 32; i += 8)
        out[(size_t)(c0 + ty + i) * R + r0 + tx] = tile[tx][ty + i];
}

// ---------- kernel 2b: per-(b,h) V transpose ----------
__global__ void transpose_v(const ushort_t* __restrict__ qkv, ushort_t* __restrict__ vt) {
    __shared__ ushort_t tile[32][33];
    int s0 = blockIdx.x * 32, d0 = blockIdx.y * 32;
    int bh = blockIdx.z;                        // b*16+h
    int b = bh >> 4, h = bh & 15;
    const ushort_t* src = qkv + (size_t)(b * SQ) * 3072 + 2048 + h * 64;
    ushort_t* dst = vt + (size_t)bh * HD * SQ;
    int tx = threadIdx.x, ty = threadIdx.y;     // block (32,8)
#pragma unroll
    for (int i = 0; i < 32; i += 8)
        tile[ty + i][tx] = src[(size_t)(s0 + ty + i) * 3072 + d0 + tx];
    __syncthreads();
#pragma unroll
    for (int i = 0; i < 32; i += 8)
        dst[(size_t)(d0 + ty + i) * SQ + s0 + tx] = tile[tx][ty + i];
}

// =====================================================================
// GEMM1: 128x128 tile, BK=64, both-sides swizzle, m97 structure.
// 768 blocks = 3/CU (implicit inter-block overlap), all 256 CUs busy.
// C[M,N] = A[M,K] @ Bt[N,K]^T + bias, bf16 out.
// =====================================================================
__global__ __launch_bounds__(256)
void gemm128_bt(const ushort_t* __restrict__ A, const ushort_t* __restrict__ Bt,
                const float* __restrict__ bias, ushort_t* __restrict__ Cout,
                int M, int N, int K, int nbn) {
    __shared__ char sA[16384];    // 128 rows x 128B, chunk-XOR swizzled
    __shared__ char sB[16384];
    const int tid = threadIdx.x;
    const int lane = tid & 63;
    const int w = tid >> 6;                     // 4 waves, 2x2
    const int wr = w >> 1, wc = w & 1;
    const int r = lane & 15, hi = lane >> 4;

    // XCD-aware bijective swizzle (grid % 8 == 0)
    const int cpx = gridDim.x >> 3;
    const int bid = blockIdx.x;
    const int x = (bid & 7) * cpx + (bid >> 3);
    const int bm = x / nbn, bn = x % nbn;
    const int m0 = bm * 128, n0 = bn * 128;

    f32x4 acc[4][4];
#pragma unroll
    for (int m = 0; m < 4; ++m)
#pragma unroll
        for (int n = 0; n < 4; ++n) acc[m][n] = (f32x4){0.f, 0.f, 0.f, 0.f};

    for (int k0 = 0; k0 < K; k0 += 64) {
        // stage A 128x64 + B 128x64: 1024 tasks each, 4 per thread,
        // inverse-swizzled global source -> linear LDS dest (rule 21)
#pragma unroll
        for (int i = 0; i < 4; ++i) {
            int task = i * 256 + tid;
            int row = task >> 3;
            int sc = (task & 7) ^ (row & 7);
            load_lds16(A + (size_t)(m0 + row) * K + k0 + sc * 8, sA + task * 16);
        }
#pragma unroll
        for (int i = 0; i < 4; ++i) {
            int task = i * 256 + tid;
            int row = task >> 3;
            int sc = (task & 7) ^ (row & 7);
            load_lds16(Bt + (size_t)(n0 + row) * K + k0 + sc * 8, sB + task * 16);
        }
        __syncthreads();

#pragma unroll
        for (int ks = 0; ks < 2; ++ks) {
            bf16x8 af[4], bfr[4];
#pragma unroll
            for (int m = 0; m < 4; ++m) {
                int row = wr * 64 + m * 16 + r;
                af[m] = *reinterpret_cast<const bf16x8*>(
                    sA + row * 128 + (((ks * 4 + hi) ^ (row & 7)) * 16));
            }
#pragma unroll
            for (int n = 0; n < 4; ++n) {
                int row = wc * 64 + n * 16 + r;
                bfr[n] = *reinterpret_cast<const bf16x8*>(
                    sB + row * 128 + (((ks * 4 + hi) ^ (row & 7)) * 16));
            }
#pragma unroll
            for (int m = 0; m < 4; ++m)
#pragma unroll
                for (int n = 0; n < 4; ++n)
                    acc[m][n] = __builtin_amdgcn_mfma_f32_16x16x32_bf16(
                        af[m], bfr[n], acc[m][n], 0, 0, 0);
        }
        __syncthreads();
    }

    // epilogue: D layout col=lane&15, row=(lane>>4)*4+j
#pragma unroll
    for (int n = 0; n < 4; ++n) {
        int colg = n0 + wc * 64 + n * 16 + r;
        float bv = bias[colg];
#pragma unroll
        for (int m = 0; m < 4; ++m) {
            int rowg = m0 + wr * 64 + m * 16 + hi * 4;
#pragma unroll
            for (int j = 0; j < 4; ++j) {
                float v = acc[m][n][j] + bv;
                Cout[(size_t)(rowg + j) * N + colg] = f2bf(v);
            }
        }
    }
}

// ---------- GEMM2: 128x64 tile, BK=64, both-sides swizzle (unchanged) ----------
__global__ __launch_bounds__(256)
void gemm_bt2(const ushort_t* __restrict__ A, const ushort_t* __restrict__ Bt,
              const float* __restrict__ bias, float* __restrict__ Cout,
              int M, int N, int K) {
    __shared__ char sA[16384];
    __shared__ char sB[8192];
    const int tid = threadIdx.x;
    const int m0 = blockIdx.y * 128, n0 = blockIdx.x * 64;
    const int w = tid >> 6, lane = tid & 63;
    const int wr = w >> 1, wc = w & 1;          // 2x2 waves, each 64x32
    const int r = lane & 15, hi = lane >> 4;

    f32x4 acc[4][2];
#pragma unroll
    for (int m = 0; m < 4; ++m)
#pragma unroll
        for (int n = 0; n < 2; ++n) acc[m][n] = (f32x4){0.f, 0.f, 0.f, 0.f};

    for (int k0 = 0; k0 < K; k0 += 64) {
#pragma unroll
        for (int i = 0; i < 4; ++i) {
            int task = i * 256 + tid;
            int row = task >> 3;
            int sc = (task & 7) ^ (row & 7);
            load_lds16(A + (size_t)(m0 + row) * K + k0 + sc * 8, sA + task * 16);
        }
#pragma unroll
        for (int i = 0; i < 2; ++i) {
            int task = i * 256 + tid;
            int row = task >> 3;
            int sc = (task & 7) ^ (row & 7);
            load_lds16(Bt + (size_t)(n0 + row) * K + k0 + sc * 8, sB + task * 16);
        }
        __syncthreads();

#pragma unroll
        for (int ks = 0; ks < 2; ++ks) {
            bf16x8 af[4], bfr[2];
#pragma unroll
            for (int m = 0; m < 4; ++m) {
                int row = wr * 64 + m * 16 + r;
                af[m] = *reinterpret_cast<const bf16x8*>(
                    sA + row * 128 + (((ks * 4 + hi) ^ (row & 7)) * 16));
            }
#pragma unroll
            for (int n = 0; n < 2; ++n) {
                int row = wc * 32 + n * 16 + r;
                bfr[n] = *reinterpret_cast<const bf16x8*>(
                    sB + row * 128 + (((ks * 4 + hi) ^ (row & 7)) * 16));
            }
#pragma unroll
            for (int m = 0; m < 4; ++m)
#pragma unroll
                for (int n = 0; n < 2; ++n)
                    acc[m][n] = __builtin_amdgcn_mfma_f32_16x16x32_bf16(
                        af[m], bfr[n], acc[m][n], 0, 0, 0);
        }
        __syncthreads();
    }

#pragma unroll
    for (int n = 0; n < 2; ++n) {
        int colg = n0 + wc * 32 + n * 16 + r;
        float bv = bias[colg];
#pragma unroll
        for (int m = 0; m < 4; ++m) {
            int rowg = m0 + wr * 64 + m * 16 + hi * 4;
#pragma unroll
            for (int j = 0; j < 4; ++j)
                Cout[(size_t)(rowg + j) * N + colg] = acc[m][n][j] + bv;
        }
    }
}

// ---------- banded attention v3: 2 barriers, P aliases K, 49KB LDS ----------
// LDS: K[192][64] swz @0 (24KB) -- after barrier#2 overwritten by
// P[64 rows][stride 400B] (25600B); VT[64][192] swz @25600 (24KB). Total 50176B
// -> 3 blocks/CU. __launch_bounds__(256,4) caps VGPR at 128 -> 16 waves/CU cap.
__global__ __launch_bounds__(256, 4)
void attn_kernel(const ushort_t* __restrict__ qkv, const ushort_t* __restrict__ vt,
                 ushort_t* __restrict__ attn_out) {
    __shared__ uint4 smem4[50176 / 16];
    char* smem = (char*)smem4;

    const int bid0 = blockIdx.x;
    const int bid = (bid0 & 7) * 128 + (bid0 >> 3);   // XCD-chunked, 1024 % 8 == 0
    const int qb = bid & 31;
    const int h = (bid >> 5) & 15;
    const int b = bid >> 9;
    const int q0 = qb * 64;
    const int kstart = (q0 - 64 > 0) ? (q0 - 64) : 0;

    const int tid = threadIdx.x;
    const int lane = tid & 63;
    const int w = tid >> 6;
    const int r = lane & 15, hi = lane >> 4;

    // ---- stage K [192][64] @0 (swizzled, zero-fill OOB) ----
#pragma unroll
    for (int i = 0; i < 6; ++i) {
        int task = i * 256 + tid;
        int row = task >> 3, ch = task & 7;
        int key = kstart + row;
        uint4 v = make_uint4(0u, 0u, 0u, 0u);
        if (key < SQ)
            v = *reinterpret_cast<const uint4*>(
                qkv + (size_t)(b * SQ + key) * 3072 + 1024 + h * 64 + ch * 8);
        int byte = row * 128 + ch * 16; byte ^= (row & 7) << 4;
        *reinterpret_cast<uint4*>(smem + byte) = v;
    }
    // ---- stage V^T [64 d][192 k] @25600 from pre-transposed vt ----
    {
        const ushort_t* vtb = vt + (size_t)(b * NH + h) * HD * SQ;
        int d = tid >> 2, cp = tid & 3;
#pragma unroll
        for (int i = 0; i < 6; ++i) {
            int c = cp + i * 4;                 // chunk 0..23 (16B each, 8 keys)
            uint4 v = make_uint4(0u, 0u, 0u, 0u);
            int k8 = kstart + c * 8;
            if (k8 < SQ)
                v = *reinterpret_cast<const uint4*>(vtb + (size_t)d * SQ + k8);
            int byte = d * 384 + (((c & 7) ^ (d & 7)) * 16) + ((c >> 3) * 128);
            *reinterpret_cast<uint4*>(smem + 25600 + byte) = v;
        }
    }

    // ---- Q directly into A-fragments (own wave's rows) ----
    const ushort_t* qrow = qkv + (size_t)(b * SQ + q0 + w * 16 + r) * 3072 + h * 64;
    bf16x8 aq0 = *reinterpret_cast<const bf16x8*>(qrow + hi * 8);
    bf16x8 aq1 = *reinterpret_cast<const bf16x8*>(qrow + 32 + hi * 8);

    __syncthreads();   // barrier #1: staging complete

    // ---- band tile range for this wave ----
    const int delta = q0 - kstart;              // 64 interior, 0 at qb==0
    const int base = w * 16 + delta;
    int tmin = (base - 64) >> 4; if (tmin < 0) tmin = 0;
    int tmax = (base + 79) >> 4;
    int tcap = (SQ - 1 - kstart) >> 4; if (tmax > tcap) tmax = tcap;
    if (tmax > 11) tmax = 11;
    const int ksmin = tmin >> 1, ksmax = tmax >> 1;

    // ---- scores: S[16q x 192k] per wave, band-skipped ----
    f32x4 acc[12];
#pragma unroll
    for (int t = 0; t < 12; ++t) acc[t] = (f32x4){0.f, 0.f, 0.f, 0.f};
#pragma unroll
    for (int t = 0; t < 12; ++t) {
        if (t < tmin || t > tmax) continue;     // wave-uniform skip
#pragma unroll
        for (int ks = 0; ks < 2; ++ks) {
            int row = t * 16 + r;
            int byte = row * 128 + ks * 64 + hi * 16; byte ^= (row & 7) << 4;
            bf16x8 bk = *reinterpret_cast<const bf16x8*>(smem + byte);
            acc[t] = __builtin_amdgcn_mfma_f32_16x16x32_bf16(
                ks == 0 ? aq0 : aq1, bk, acc[t], 0, 0, 0);
        }
    }

    // ---- mask + scale + softmax ----
    float mrow[4], lrow[4];
#pragma unroll
    for (int t = 0; t < 12; ++t) {
        if (t < tmin || t > tmax) continue;
        int key = kstart + t * 16 + r;
#pragma unroll
        for (int j = 0; j < 4; ++j) {
            int qrow_g = q0 + w * 16 + hi * 4 + j;
            int dd = key - qrow_g; if (dd < 0) dd = -dd;
            bool valid = (key < SQ) && (dd <= 64);
            acc[t][j] = valid ? acc[t][j] * 0.125f : -1e30f;
        }
    }
#pragma unroll
    for (int j = 0; j < 4; ++j) {
        float m = -1e30f;
#pragma unroll
        for (int t = 0; t < 12; ++t) {
            if (t < tmin || t > tmax) continue;
            m = fmaxf(m, acc[t][j]);
        }
        m = fmaxf(m, __shfl_xor(m, 1));
        m = fmaxf(m, __shfl_xor(m, 2));
        m = fmaxf(m, __shfl_xor(m, 4));
        m = fmaxf(m, __shfl_xor(m, 8));
        mrow[j] = m;
    }
#pragma unroll
    for (int j = 0; j < 4; ++j) {
        float s = 0.f;
#pragma unroll
        for (int t = 0; t < 12; ++t) {
            if (t < tmin || t > tmax) continue;
            float p = __expf(acc[t][j] - mrow[j]);
            acc[t][j] = p;
            s += p;
        }
        s += __shfl_xor(s, 1);
        s += __shfl_xor(s, 2);
        s += __shfl_xor(s, 4);
        s += __shfl_xor(s, 8);
        lrow[j] = s;
    }

    __syncthreads();   // barrier #2: all QK^T reads of K done; P may overwrite

    // ---- write P @0 (stride 400B), own wave's 16 rows only ----
#pragma unroll
    for (int t = 0; t < 12; ++t) {
        int col = t * 16 + r;
        bool inb = (t >= tmin) && (t <= tmax);
#pragma unroll
        for (int j = 0; j < 4; ++j) {
            int rowL = w * 16 + hi * 4 + j;
            ushort_t pv = inb ? f2bf(acc[t][j]) : (ushort_t)0;
            *reinterpret_cast<ushort_t*>(smem + rowL * 400 + col * 2) = pv;
        }
    }
    // same-wave write->read dependency: compiler inserts lgkmcnt; no barrier.

    // ---- PV: O[16q x 64d]; band-skipped k-chunks ----
    f32x4 oacc[4];
#pragma unroll
    for (int dt = 0; dt < 4; ++dt) oacc[dt] = (f32x4){0.f, 0.f, 0.f, 0.f};
#pragma unroll
    for (int ks = 0; ks < 6; ++ks) {
        if (ks < ksmin || ks > ksmax) continue;
        int k0 = ks * 32 + hi * 8;
        bf16x8 ap = *reinterpret_cast<const bf16x8*>(
            smem + (w * 16 + r) * 400 + k0 * 2);
        int cch = ks * 4 + hi;                  // 16B chunk index 0..23
#pragma unroll
        for (int dt = 0; dt < 4; ++dt) {
            int d = dt * 16 + r;
            int byte = d * 384 + (((cch & 7) ^ (d & 7)) * 16) + ((cch >> 3) * 128);
            bf16x8 bv = *reinterpret_cast<const bf16x8*>(smem + 25600 + byte);
            oacc[dt] = __builtin_amdgcn_mfma_f32_16x16x32_bf16(ap, bv, oacc[dt], 0, 0, 0);
        }
    }

    // ---- normalize + store ----
    float inv[4];
#pragma unroll
    for (int j = 0; j < 4; ++j) inv[j] = 1.0f / lrow[j];
#pragma unroll
    for (int dt = 0; dt < 4; ++dt) {
        int d = dt * 16 + r;
#pragma unroll
        for (int j = 0; j < 4; ++j) {
            int q = q0 + w * 16 + hi * 4 + j;
            attn_out[(size_t)(b * SQ + q) * 1024 + h * 64 + d] = f2bf(oacc[dt][j] * inv[j]);
        }
    }
}

// ---------- launch ----------
extern "C" void kernel_launch(void* const* d_in, const int* in_sizes, int n_in,
                              void* d_out, int out_size, void* d_ws, size_t ws_size,
                              hipStream_t stream) {
    const float* x     = (const float*)d_in[0];
    const float* w_qkv = (const float*)d_in[1];
    const float* b_qkv = (const float*)d_in[2];
    const float* w_out = (const float*)d_in[3];
    const float* b_out = (const float*)d_in[4];
    float* out = (float*)d_out;

    char* ws = (char*)d_ws;
    ushort_t* xb    = (ushort_t*)(ws);                       // 8 MB  [4096][1024]
    ushort_t* wqkvT = (ushort_t*)(ws + 8388608);             // 6 MB  [3072][1024]
    ushort_t* woutT = (ushort_t*)(ws + 14680064);            // 2 MB  [1024][1024]
    ushort_t* qkv   = (ushort_t*)(ws + 16777216);            // 24 MB [4096][3072]
    ushort_t* aout  = (ushort_t*)(ws + 41943040);            // 8 MB  [4096][1024]
    ushort_t* vtbuf = (ushort_t*)(ws + 50331648);            // 8 MB  [32][64][2048]

    cvt_x<<<1024, 256, 0, stream>>>(x, xb, 4096 * 1024 / 4);
    transpose_cvt<<<dim3(96, 32), dim3(32, 8), 0, stream>>>(w_qkv, wqkvT, 1024, 3072);
    transpose_cvt<<<dim3(32, 32), dim3(32, 8), 0, stream>>>(w_out, woutT, 1024, 1024);

    // GEMM1: 4096x3072x1024, 128^2 tiles -> grid 32*24 = 768 = 3 blocks/CU
    gemm128_bt<<<768, 256, 0, stream>>>(xb, wqkvT, b_qkv, qkv, 4096, 3072, 1024, 24);
    transpose_v<<<dim3(64, 2, 32), dim3(32, 8), 0, stream>>>(qkv, vtbuf);
    attn_kernel<<<1024, 256, 0, stream>>>(qkv, vtbuf, aout);
    gemm_bt2<<<dim3(16, 32), 256, 0, stream>>>(aout, woutT, b_out, out, 4096, 1024, 1024);
}

// Round 10
// 81.883 us; speedup vs baseline: 1.2172x; 1.2172x over previous
//
#include <hip/hip_runtime.h>
#include <hip/hip_bf16.h>

// ---------- types ----------
typedef short bf16x8 __attribute__((ext_vector_type(8)));   // 8 bf16 = 4 VGPR
typedef float f32x4 __attribute__((ext_vector_type(4)));
typedef unsigned short ushort_t;

#define SQ 2048
#define DIM 1024
#define NH 16
#define HD 64

__device__ __forceinline__ ushort_t f2bf(float f) {
    __hip_bfloat16 h = __float2bfloat16(f);     // HW v_cvt, RNE
    return *reinterpret_cast<ushort_t*>(&h);
}

__device__ __forceinline__ void load_lds16(const void* g, void* l) {
    __builtin_amdgcn_global_load_lds(
        (const __attribute__((address_space(1))) unsigned int*)g,
        (__attribute__((address_space(3))) unsigned int*)l, 16, 0, 0);
}

// ---------- fused prep: cvt_x | transpose(w_qkv) | transpose(w_out) ----------
// blocks 0..1023: cvt_x; 1024..4095: w_qkv 32x32 transpose tiles; 4096..5119: w_out.
__global__ void prep_kernel(const float* __restrict__ x, ushort_t* __restrict__ xb,
                            const float* __restrict__ w_qkv, ushort_t* __restrict__ wqkvT,
                            const float* __restrict__ w_out, ushort_t* __restrict__ woutT) {
    __shared__ ushort_t tile[32][33];
    const int bid = blockIdx.x;
    const int tid = threadIdx.x;
    if (bid < 1024) {
        // cvt_x: 4M float4 tasks over 1024 blocks x 256 threads
        int i = bid * 256 + tid;
        const int stride = 1024 * 256;
        const int n4 = 4096 * 1024 / 4;
        for (; i < n4; i += stride) {
            float4 f = reinterpret_cast<const float4*>(x)[i];
            ushort4 o;
            o.x = f2bf(f.x); o.y = f2bf(f.y); o.z = f2bf(f.z); o.w = f2bf(f.w);
            reinterpret_cast<ushort4*>(xb)[i] = o;
        }
        return;
    }
    const float* in; ushort_t* out; int R, C, idx;
    if (bid < 4096) { idx = bid - 1024; in = w_qkv; out = wqkvT; R = 1024; C = 3072;
        // grid was (96, 32): c-tiles 96, r-tiles 32
        int cx = idx % 96, ry = idx / 96;
        int c0 = cx * 32, r0 = ry * 32;
        int tx = tid & 31, ty = tid >> 5;
#pragma unroll
        for (int i = 0; i < 32; i += 8)
            tile[ty + i][tx] = f2bf(in[(size_t)(r0 + ty + i) * C + c0 + tx]);
        __syncthreads();
#pragma unroll
        for (int i = 0; i < 32; i += 8)
            out[(size_t)(c0 + ty + i) * R + r0 + tx] = tile[tx][ty + i];
        return;
    }
    idx = bid - 4096; in = w_out; out = woutT; R = 1024; C = 1024;
    int cx = idx % 32, ry = idx / 32;
    int c0 = cx * 32, r0 = ry * 32;
    int tx = tid & 31, ty = tid >> 5;
#pragma unroll
    for (int i = 0; i < 32; i += 8)
        tile[ty + i][tx] = f2bf(in[(size_t)(r0 + ty + i) * C + c0 + tx]);
    __syncthreads();
#pragma unroll
    for (int i = 0; i < 32; i += 8)
        out[(size_t)(c0 + ty + i) * R + r0 + tx] = tile[tx][ty + i];
}

// ---------- kernel 2b: per-(b,h) V transpose ----------
__global__ void transpose_v(const ushort_t* __restrict__ qkv, ushort_t* __restrict__ vt) {
    __shared__ ushort_t tile[32][33];
    int s0 = blockIdx.x * 32, d0 = blockIdx.y * 32;
    int bh = blockIdx.z;                        // b*16+h
    int b = bh >> 4, h = bh & 15;
    const ushort_t* src = qkv + (size_t)(b * SQ) * 3072 + 2048 + h * 64;
    ushort_t* dst = vt + (size_t)bh * HD * SQ;
    int tx = threadIdx.x, ty = threadIdx.y;     // block (32,8)
#pragma unroll
    for (int i = 0; i < 32; i += 8)
        tile[ty + i][tx] = src[(size_t)(s0 + ty + i) * 3072 + d0 + tx];
    __syncthreads();
#pragma unroll
    for (int i = 0; i < 32; i += 8)
        dst[(size_t)(d0 + ty + i) * SQ + s0 + tx] = tile[tx][ty + i];
}

// =====================================================================
// GEMM1: 256x192 tile, 8 waves (2Mx4N), per-wave 128x48, BK=64, 4-phase
// (M-quadrant) schedule, 2 K-tiles/iter, unit-staged (8KB = 1 load/thread).
// Grid 16x16 = 256 blocks = EXACTLY 1 block/CU -> 100% CU coverage.
// vmcnt ledger verified: prologue vmcnt(2); ph2/ph4 vmcnt(2).
// =====================================================================

#define STAGE_U(Gptr, ldk, grow0, kcol, regionbase)                          \
  { int row_ = tid >> 3;                                                      \
    int sc_ = (tid & 7) ^ (row_ & 7);                                         \
    load_lds16((Gptr) + (size_t)((grow0) + row_) * (ldk) + (kcol) + sc_ * 8,  \
               (regionbase) + tid * 16); }

#define DS_A192(BASE, EXTRA)                                                  \
  _Pragma("unroll") for (int kk_ = 0; kk_ < 2; ++kk_)                         \
  _Pragma("unroll") for (int m_ = 0; m_ < 4; ++m_)                            \
    a[kk_][m_] = *reinterpret_cast<const bf16x8*>((BASE) + (EXTRA) + offA[kk_][m_]);

#define DS_B192(BASE)                                                         \
  _Pragma("unroll") for (int kk_ = 0; kk_ < 2; ++kk_)                         \
  _Pragma("unroll") for (int n_ = 0; n_ < 3; ++n_)                            \
    b[kk_][n_] = *reinterpret_cast<const bf16x8*>((BASE) + offB[kk_][n_]);

#define BAR_LGKM                                                              \
  __builtin_amdgcn_s_barrier();                                               \
  asm volatile("s_waitcnt lgkmcnt(0)" ::: "memory");                          \
  __builtin_amdgcn_sched_barrier(0);

#define MFMA_Q(MQ)                                                            \
  __builtin_amdgcn_s_setprio(1);                                              \
  _Pragma("unroll") for (int kk_ = 0; kk_ < 2; ++kk_)                         \
  _Pragma("unroll") for (int m_ = 0; m_ < 4; ++m_)                            \
  _Pragma("unroll") for (int n_ = 0; n_ < 3; ++n_)                            \
    acc[(MQ)*4 + m_][n_] = __builtin_amdgcn_mfma_f32_16x16x32_bf16(           \
        a[kk_][m_], b[kk_][n_], acc[(MQ)*4 + m_][n_], 0, 0, 0);               \
  __builtin_amdgcn_s_setprio(0);

__global__ __launch_bounds__(512, 2)
void gemm192_bt(const ushort_t* __restrict__ A, const ushort_t* __restrict__ Bt,
                const float* __restrict__ bias, ushort_t* __restrict__ Cout,
                int M, int N, int K, int nbn) {
    __shared__ char sm[114688];
    const int tid = threadIdx.x;
    const int lane = tid & 63;
    const int w = tid >> 6;                 // 0..7
    const int wm = w >> 2, wn = w & 3;      // 2M x 4N waves
    const int r = lane & 15, hi = lane >> 4;

    // XCD-aware bijective swizzle (grid 256 % 8 == 0)
    const int cpx = gridDim.x >> 3;
    const int bid = blockIdx.x;
    const int x = (bid & 7) * cpx + (bid >> 3);
    const int bm = x / nbn, bn = x % nbn;
    const int m0 = bm * 256, n0 = bn * 192;

    const int NT = K >> 6;                  // 16 K-tiles
    const int NI = NT >> 1;                 // 8 iterations

    // LDS: A0 32KB @0, B0 24KB @32768, A1 32KB @57344, B1 24KB @90112
    char* const A0 = sm;
    char* const B0 = sm + 32768;
    char* const A1 = sm + 57344;
    char* const B1 = sm + 90112;

    // ds_read byte offsets (mq=0; mq=1 adds 8192 since 64 rows x 128B, row&7 preserved)
    int offA[2][4], offB[2][3];
#pragma unroll
    for (int kk = 0; kk < 2; ++kk) {
#pragma unroll
        for (int m = 0; m < 4; ++m) {
            int rowL = wm * 128 + m * 16 + r;
            offA[kk][m] = rowL * 128 + (((kk * 4 + hi) ^ (rowL & 7)) * 16);
        }
#pragma unroll
        for (int n = 0; n < 3; ++n) {
            int rowL = wn * 48 + n * 16 + r;
            offB[kk][n] = rowL * 128 + (((kk * 4 + hi) ^ (rowL & 7)) * 16);
        }
    }

    f32x4 acc[8][3];
#pragma unroll
    for (int am = 0; am < 8; ++am)
#pragma unroll
        for (int an = 0; an < 3; ++an) acc[am][an] = (f32x4){0.f, 0.f, 0.f, 0.f};

    bf16x8 a[2][4], b[2][3];

    // ---- prologue: T0 full (A0 u0-3, B0 u0-2), T1 A1 u0,u2. vmcnt(2). ----
    STAGE_U(A,  K, m0,        0, A0);
    STAGE_U(A,  K, m0 + 64,   0, A0 + 8192);
    STAGE_U(A,  K, m0 + 128,  0, A0 + 16384);
    STAGE_U(A,  K, m0 + 192,  0, A0 + 24576);
    STAGE_U(Bt, K, n0,        0, B0);
    STAGE_U(Bt, K, n0 + 64,   0, B0 + 8192);
    STAGE_U(Bt, K, n0 + 128,  0, B0 + 16384);
    STAGE_U(A,  K, m0,       64, A1);
    STAGE_U(A,  K, m0 + 128, 64, A1 + 16384);
    asm volatile("s_waitcnt vmcnt(2)" ::: "memory");
    __builtin_amdgcn_s_barrier();

    for (int i = 0; i < NI; ++i) {
        const int k1 = (2 * i + 1) * 64;              // < K always
        const int k2 = ((2 * i + 2) % NT) * 64;       // wraps harmlessly last iter
        const int k3 = ((2 * i + 3) % NT) * 64;

        // ph1: compute T0 mq=0 (reads A0 u0,u2 + B0); stage A1u1,u3 + B1 u0-2 (T1)
        STAGE_U(A,  K, m0 + 64,  k1, A1 + 8192);
        STAGE_U(A,  K, m0 + 192, k1, A1 + 24576);
        STAGE_U(Bt, K, n0,       k1, B1);
        STAGE_U(Bt, K, n0 + 64,  k1, B1 + 8192);
        STAGE_U(Bt, K, n0 + 128, k1, B1 + 16384);
        DS_A192(A0, 0); DS_B192(B0);
        BAR_LGKM; MFMA_Q(0);
        __builtin_amdgcn_s_barrier();

        // ph2: compute T0 mq=1 (reads A0 u1,u3; B held); stage A0 u0,u2 (T2)
        STAGE_U(A, K, m0,       k2, A0);
        STAGE_U(A, K, m0 + 128, k2, A0 + 16384);
        DS_A192(A0, 8192);
        BAR_LGKM; MFMA_Q(1);
        asm volatile("s_waitcnt vmcnt(2)" ::: "memory");
        __builtin_amdgcn_s_barrier();

        // ph3: compute T1 mq=0 (reads A1 u0,u2 + B1); stage A0 u1,u3 + B0 u0-2 (T2)
        STAGE_U(A,  K, m0 + 64,  k2, A0 + 8192);
        STAGE_U(A,  K, m0 + 192, k2, A0 + 24576);
        STAGE_U(Bt, K, n0,       k2, B0);
        STAGE_U(Bt, K, n0 + 64,  k2, B0 + 8192);
        STAGE_U(Bt, K, n0 + 128, k2, B0 + 16384);
        DS_A192(A1, 0); DS_B192(B1);
        BAR_LGKM; MFMA_Q(0);
        __builtin_amdgcn_s_barrier();

        // ph4: compute T1 mq=1 (reads A1 u1,u3; B held); stage A1 u0,u2 (T3)
        STAGE_U(A, K, m0,       k3, A1);
        STAGE_U(A, K, m0 + 128, k3, A1 + 16384);
        DS_A192(A1, 8192);
        BAR_LGKM; MFMA_Q(1);
        asm volatile("s_waitcnt vmcnt(2)" ::: "memory");
        __builtin_amdgcn_s_barrier();
    }

    // ---- epilogue: row = m0 + wm*128 + (am>>2)*64 + (am&3)*16 + hi*4 + j ----
#pragma unroll
    for (int am = 0; am < 8; ++am) {
        int rowg = m0 + wm * 128 + (am >> 2) * 64 + (am & 3) * 16 + hi * 4;
#pragma unroll
        for (int an = 0; an < 3; ++an) {
            int colg = n0 + wn * 48 + an * 16 + r;
            float bv = bias[colg];
#pragma unroll
            for (int j = 0; j < 4; ++j) {
                float v = acc[am][an][j] + bv;
                Cout[(size_t)(rowg + j) * N + colg] = f2bf(v);
            }
        }
    }
}

// ---------- GEMM2: 128x64 tile, BK=64, both-sides swizzle (R8, unchanged) ----------
__global__ __launch_bounds__(256)
void gemm_bt2(const ushort_t* __restrict__ A, const ushort_t* __restrict__ Bt,
              const float* __restrict__ bias, float* __restrict__ Cout,
              int M, int N, int K) {
    __shared__ char sA[16384];
    __shared__ char sB[8192];
    const int tid = threadIdx.x;
    const int m0 = blockIdx.y * 128, n0 = blockIdx.x * 64;
    const int w = tid >> 6, lane = tid & 63;
    const int wr = w >> 1, wc = w & 1;          // 2x2 waves, each 64x32
    const int r = lane & 15, hi = lane >> 4;

    f32x4 acc[4][2];
#pragma unroll
    for (int m = 0; m < 4; ++m)
#pragma unroll
        for (int n = 0; n < 2; ++n) acc[m][n] = (f32x4){0.f, 0.f, 0.f, 0.f};

    for (int k0 = 0; k0 < K; k0 += 64) {
#pragma unroll
        for (int i = 0; i < 4; ++i) {
            int task = i * 256 + tid;
            int row = task >> 3;
            int sc = (task & 7) ^ (row & 7);
            load_lds16(A + (size_t)(m0 + row) * K + k0 + sc * 8, sA + task * 16);
        }
#pragma unroll
        for (int i = 0; i < 2; ++i) {
            int task = i * 256 + tid;
            int row = task >> 3;
            int sc = (task & 7) ^ (row & 7);
            load_lds16(Bt + (size_t)(n0 + row) * K + k0 + sc * 8, sB + task * 16);
        }
        __syncthreads();

#pragma unroll
        for (int ks = 0; ks < 2; ++ks) {
            bf16x8 af[4], bfr[2];
#pragma unroll
            for (int m = 0; m < 4; ++m) {
                int row = wr * 64 + m * 16 + r;
                af[m] = *reinterpret_cast<const bf16x8*>(
                    sA + row * 128 + (((ks * 4 + hi) ^ (row & 7)) * 16));
            }
#pragma unroll
            for (int n = 0; n < 2; ++n) {
                int row = wc * 32 + n * 16 + r;
                bfr[n] = *reinterpret_cast<const bf16x8*>(
                    sB + row * 128 + (((ks * 4 + hi) ^ (row & 7)) * 16));
            }
#pragma unroll
            for (int m = 0; m < 4; ++m)
#pragma unroll
                for (int n = 0; n < 2; ++n)
                    acc[m][n] = __builtin_amdgcn_mfma_f32_16x16x32_bf16(
                        af[m], bfr[n], acc[m][n], 0, 0, 0);
        }
        __syncthreads();
    }

#pragma unroll
    for (int n = 0; n < 2; ++n) {
        int colg = n0 + wc * 32 + n * 16 + r;
        float bv = bias[colg];
#pragma unroll
        for (int m = 0; m < 4; ++m) {
            int rowg = m0 + wr * 64 + m * 16 + hi * 4;
#pragma unroll
            for (int j = 0; j < 4; ++j)
                Cout[(size_t)(rowg + j) * N + colg] = acc[m][n][j] + bv;
        }
    }
}

// ---------- banded attention v3 (R8, unchanged): 2 barriers, P aliases K ----------
__global__ __launch_bounds__(256, 4)
void attn_kernel(const ushort_t* __restrict__ qkv, const ushort_t* __restrict__ vt,
                 ushort_t* __restrict__ attn_out) {
    __shared__ uint4 smem4[50176 / 16];
    char* smem = (char*)smem4;

    const int bid0 = blockIdx.x;
    const int bid = (bid0 & 7) * 128 + (bid0 >> 3);   // XCD-chunked
    const int qb = bid & 31;
    const int h = (bid >> 5) & 15;
    const int b = bid >> 9;
    const int q0 = qb * 64;
    const int kstart = (q0 - 64 > 0) ? (q0 - 64) : 0;

    const int tid = threadIdx.x;
    const int lane = tid & 63;
    const int w = tid >> 6;
    const int r = lane & 15, hi = lane >> 4;

#pragma unroll
    for (int i = 0; i < 6; ++i) {
        int task = i * 256 + tid;
        int row = task >> 3, ch = task & 7;
        int key = kstart + row;
        uint4 v = make_uint4(0u, 0u, 0u, 0u);
        if (key < SQ)
            v = *reinterpret_cast<const uint4*>(
                qkv + (size_t)(b * SQ + key) * 3072 + 1024 + h * 64 + ch * 8);
        int byte = row * 128 + ch * 16; byte ^= (row & 7) << 4;
        *reinterpret_cast<uint4*>(smem + byte) = v;
    }
    {
        const ushort_t* vtb = vt + (size_t)(b * NH + h) * HD * SQ;
        int d = tid >> 2, cp = tid & 3;
#pragma unroll
        for (int i = 0; i < 6; ++i) {
            int c = cp + i * 4;
            uint4 v = make_uint4(0u, 0u, 0u, 0u);
            int k8 = kstart + c * 8;
            if (k8 < SQ)
                v = *reinterpret_cast<const uint4*>(vtb + (size_t)d * SQ + k8);
            int byte = d * 384 + (((c & 7) ^ (d & 7)) * 16) + ((c >> 3) * 128);
            *reinterpret_cast<uint4*>(smem + 25600 + byte) = v;
        }
    }

    const ushort_t* qrow = qkv + (size_t)(b * SQ + q0 + w * 16 + r) * 3072 + h * 64;
    bf16x8 aq0 = *reinterpret_cast<const bf16x8*>(qrow + hi * 8);
    bf16x8 aq1 = *reinterpret_cast<const bf16x8*>(qrow + 32 + hi * 8);

    __syncthreads();   // barrier #1

    const int delta = q0 - kstart;
    const int base = w * 16 + delta;
    int tmin = (base - 64) >> 4; if (tmin < 0) tmin = 0;
    int tmax = (base + 79) >> 4;
    int tcap = (SQ - 1 - kstart) >> 4; if (tmax > tcap) tmax = tcap;
    if (tmax > 11) tmax = 11;
    const int ksmin = tmin >> 1, ksmax = tmax >> 1;

    f32x4 acc[12];
#pragma unroll
    for (int t = 0; t < 12; ++t) acc[t] = (f32x4){0.f, 0.f, 0.f, 0.f};
#pragma unroll
    for (int t = 0; t < 12; ++t) {
        if (t < tmin || t > tmax) continue;
#pragma unroll
        for (int ks = 0; ks < 2; ++ks) {
            int row = t * 16 + r;
            int byte = row * 128 + ks * 64 + hi * 16; byte ^= (row & 7) << 4;
            bf16x8 bk = *reinterpret_cast<const bf16x8*>(smem + byte);
            acc[t] = __builtin_amdgcn_mfma_f32_16x16x32_bf16(
                ks == 0 ? aq0 : aq1, bk, acc[t], 0, 0, 0);
        }
    }

    float mrow[4], lrow[4];
#pragma unroll
    for (int t = 0; t < 12; ++t) {
        if (t < tmin || t > tmax) continue;
        int key = kstart + t * 16 + r;
#pragma unroll
        for (int j = 0; j < 4; ++j) {
            int qrow_g = q0 + w * 16 + hi * 4 + j;
            int dd = key - qrow_g; if (dd < 0) dd = -dd;
            bool valid = (key < SQ) && (dd <= 64);
            acc[t][j] = valid ? acc[t][j] * 0.125f : -1e30f;
        }
    }
#pragma unroll
    for (int j = 0; j < 4; ++j) {
        float m = -1e30f;
#pragma unroll
        for (int t = 0; t < 12; ++t) {
            if (t < tmin || t > tmax) continue;
            m = fmaxf(m, acc[t][j]);
        }
        m = fmaxf(m, __shfl_xor(m, 1));
        m = fmaxf(m, __shfl_xor(m, 2));
        m = fmaxf(m, __shfl_xor(m, 4));
        m = fmaxf(m, __shfl_xor(m, 8));
        mrow[j] = m;
    }
#pragma unroll
    for (int j = 0; j < 4; ++j) {
        float s = 0.f;
#pragma unroll
        for (int t = 0; t < 12; ++t) {
            if (t < tmin || t > tmax) continue;
            float p = __expf(acc[t][j] - mrow[j]);
            acc[t][j] = p;
            s += p;
        }
        s += __shfl_xor(s, 1);
        s += __shfl_xor(s, 2);
        s += __shfl_xor(s, 4);
        s += __shfl_xor(s, 8);
        lrow[j] = s;
    }

    __syncthreads();   // barrier #2: K reads done; P may overwrite

#pragma unroll
    for (int t = 0; t < 12; ++t) {
        int col = t * 16 + r;
        bool inb = (t >= tmin) && (t <= tmax);
#pragma unroll
        for (int j = 0; j < 4; ++j) {
            int rowL = w * 16 + hi * 4 + j;
            ushort_t pv = inb ? f2bf(acc[t][j]) : (ushort_t)0;
            *reinterpret_cast<ushort_t*>(smem + rowL * 400 + col * 2) = pv;
        }
    }

    f32x4 oacc[4];
#pragma unroll
    for (int dt = 0; dt < 4; ++dt) oacc[dt] = (f32x4){0.f, 0.f, 0.f, 0.f};
#pragma unroll
    for (int ks = 0; ks < 6; ++ks) {
        if (ks < ksmin || ks > ksmax) continue;
        int k0 = ks * 32 + hi * 8;
        bf16x8 ap = *reinterpret_cast<const bf16x8*>(
            smem + (w * 16 + r) * 400 + k0 * 2);
        int cch = ks * 4 + hi;
#pragma unroll
        for (int dt = 0; dt < 4; ++dt) {
            int d = dt * 16 + r;
            int byte = d * 384 + (((cch & 7) ^ (d & 7)) * 16) + ((cch >> 3) * 128);
            bf16x8 bv = *reinterpret_cast<const bf16x8*>(smem + 25600 + byte);
            oacc[dt] = __builtin_amdgcn_mfma_f32_16x16x32_bf16(ap, bv, oacc[dt], 0, 0, 0);
        }
    }

    float inv[4];
#pragma unroll
    for (int j = 0; j < 4; ++j) inv[j] = 1.0f / lrow[j];
#pragma unroll
    for (int dt = 0; dt < 4; ++dt) {
        int d = dt * 16 + r;
#pragma unroll
        for (int j = 0; j < 4; ++j) {
            int q = q0 + w * 16 + hi * 4 + j;
            attn_out[(size_t)(b * SQ + q) * 1024 + h * 64 + d] = f2bf(oacc[dt][j] * inv[j]);
        }
    }
}

// ---------- launch ----------
extern "C" void kernel_launch(void* const* d_in, const int* in_sizes, int n_in,
                              void* d_out, int out_size, void* d_ws, size_t ws_size,
                              hipStream_t stream) {
    const float* x     = (const float*)d_in[0];
    const float* w_qkv = (const float*)d_in[1];
    const float* b_qkv = (const float*)d_in[2];
    const float* w_out = (const float*)d_in[3];
    const float* b_out = (const float*)d_in[4];
    float* out = (float*)d_out;

    char* ws = (char*)d_ws;
    ushort_t* xb    = (ushort_t*)(ws);                       // 8 MB  [4096][1024]
    ushort_t* wqkvT = (ushort_t*)(ws + 8388608);             // 6 MB  [3072][1024]
    ushort_t* woutT = (ushort_t*)(ws + 14680064);            // 2 MB  [1024][1024]
    ushort_t* qkv   = (ushort_t*)(ws + 16777216);            // 24 MB [4096][3072]
    ushort_t* aout  = (ushort_t*)(ws + 41943040);            // 8 MB  [4096][1024]
    ushort_t* vtbuf = (ushort_t*)(ws + 50331648);            // 8 MB  [32][64][2048]

    prep_kernel<<<5120, 256, 0, stream>>>(x, xb, w_qkv, wqkvT, w_out, woutT);

    // GEMM1: 4096x3072x1024, 256x192 tiles -> grid 16*16 = 256 = 1 block/CU
    gemm192_bt<<<256, 512, 0, stream>>>(xb, wqkvT, b_qkv, qkv, 4096, 3072, 1024, 16);
    transpose_v<<<dim3(64, 2, 32), dim3(32, 8), 0, stream>>>(qkv, vtbuf);
    attn_kernel<<<1024, 256, 0, stream>>>(qkv, vtbuf, aout);
    gemm_bt2<<<dim3(16, 32), 256, 0, stream>>>(aout, woutT, b_out, out, 4096, 1024, 1024);
}

// Round 11
// 78.417 us; speedup vs baseline: 1.2710x; 1.0442x over previous
//
#include <hip/hip_runtime.h>
#include <hip/hip_bf16.h>

// ---------- types ----------
typedef short bf16x8 __attribute__((ext_vector_type(8)));   // 8 bf16 = 4 VGPR
typedef float f32x4 __attribute__((ext_vector_type(4)));
typedef unsigned short ushort_t;

#define SQ 2048
#define DIM 1024
#define NH 16
#define HD 64

__device__ __forceinline__ ushort_t f2bf(float f) {
    __hip_bfloat16 h = __float2bfloat16(f);     // HW v_cvt, RNE
    return *reinterpret_cast<ushort_t*>(&h);
}

__device__ __forceinline__ void load_lds16(const void* g, void* l) {
    __builtin_amdgcn_global_load_lds(
        (const __attribute__((address_space(1))) unsigned int*)g,
        (__attribute__((address_space(3))) unsigned int*)l, 16, 0, 0);
}

// ---------- fused prep: cvt_x | transpose(w_qkv) | transpose(w_out) ----------
__global__ void prep_kernel(const float* __restrict__ x, ushort_t* __restrict__ xb,
                            const float* __restrict__ w_qkv, ushort_t* __restrict__ wqkvT,
                            const float* __restrict__ w_out, ushort_t* __restrict__ woutT) {
    __shared__ ushort_t tile[32][33];
    const int bid = blockIdx.x;
    const int tid = threadIdx.x;
    if (bid < 1024) {
        int i = bid * 256 + tid;
        const int stride = 1024 * 256;
        const int n4 = 4096 * 1024 / 4;
        for (; i < n4; i += stride) {
            float4 f = reinterpret_cast<const float4*>(x)[i];
            ushort4 o;
            o.x = f2bf(f.x); o.y = f2bf(f.y); o.z = f2bf(f.z); o.w = f2bf(f.w);
            reinterpret_cast<ushort4*>(xb)[i] = o;
        }
        return;
    }
    const float* in; ushort_t* out; int R, C, idx;
    if (bid < 4096) { idx = bid - 1024; in = w_qkv; out = wqkvT; R = 1024; C = 3072;
        int cx = idx % 96, ry = idx / 96;
        int c0 = cx * 32, r0 = ry * 32;
        int tx = tid & 31, ty = tid >> 5;
#pragma unroll
        for (int i = 0; i < 32; i += 8)
            tile[ty + i][tx] = f2bf(in[(size_t)(r0 + ty + i) * C + c0 + tx]);
        __syncthreads();
#pragma unroll
        for (int i = 0; i < 32; i += 8)
            out[(size_t)(c0 + ty + i) * R + r0 + tx] = tile[tx][ty + i];
        return;
    }
    idx = bid - 4096; in = w_out; out = woutT; R = 1024; C = 1024;
    int cx = idx % 32, ry = idx / 32;
    int c0 = cx * 32, r0 = ry * 32;
    int tx = tid & 31, ty = tid >> 5;
#pragma unroll
    for (int i = 0; i < 32; i += 8)
        tile[ty + i][tx] = f2bf(in[(size_t)(r0 + ty + i) * C + c0 + tx]);
    __syncthreads();
#pragma unroll
    for (int i = 0; i < 32; i += 8)
        out[(size_t)(c0 + ty + i) * R + r0 + tx] = tile[tx][ty + i];
}

// ---------- kernel 2b: per-(b,h) V transpose ----------
__global__ void transpose_v(const ushort_t* __restrict__ qkv, ushort_t* __restrict__ vt) {
    __shared__ ushort_t tile[32][33];
    int s0 = blockIdx.x * 32, d0 = blockIdx.y * 32;
    int bh = blockIdx.z;                        // b*16+h
    int b = bh >> 4, h = bh & 15;
    const ushort_t* src = qkv + (size_t)(b * SQ) * 3072 + 2048 + h * 64;
    ushort_t* dst = vt + (size_t)bh * HD * SQ;
    int tx = threadIdx.x, ty = threadIdx.y;     // block (32,8)
#pragma unroll
    for (int i = 0; i < 32; i += 8)
        tile[ty + i][tx] = src[(size_t)(s0 + ty + i) * 3072 + d0 + tx];
    __syncthreads();
#pragma unroll
    for (int i = 0; i < 32; i += 8)
        dst[(size_t)(d0 + ty + i) * SQ + s0 + tx] = tile[tx][ty + i];
}

// =====================================================================
// GEMM1 (unchanged R10): 256x192 tile, 4-phase counted-vmcnt, 256 blocks.
// =====================================================================

#define STAGE_U(Gptr, ldk, grow0, kcol, regionbase)                          \
  { int row_ = tid >> 3;                                                      \
    int sc_ = (tid & 7) ^ (row_ & 7);                                         \
    load_lds16((Gptr) + (size_t)((grow0) + row_) * (ldk) + (kcol) + sc_ * 8,  \
               (regionbase) + tid * 16); }

#define DS_A192(BASE, EXTRA)                                                  \
  _Pragma("unroll") for (int kk_ = 0; kk_ < 2; ++kk_)                         \
  _Pragma("unroll") for (int m_ = 0; m_ < 4; ++m_)                            \
    a[kk_][m_] = *reinterpret_cast<const bf16x8*>((BASE) + (EXTRA) + offA[kk_][m_]);

#define DS_B192(BASE)                                                         \
  _Pragma("unroll") for (int kk_ = 0; kk_ < 2; ++kk_)                         \
  _Pragma("unroll") for (int n_ = 0; n_ < 3; ++n_)                            \
    b[kk_][n_] = *reinterpret_cast<const bf16x8*>((BASE) + offB[kk_][n_]);

#define BAR_LGKM                                                              \
  __builtin_amdgcn_s_barrier();                                               \
  asm volatile("s_waitcnt lgkmcnt(0)" ::: "memory");                          \
  __builtin_amdgcn_sched_barrier(0);

#define MFMA_Q(MQ)                                                            \
  __builtin_amdgcn_s_setprio(1);                                              \
  _Pragma("unroll") for (int kk_ = 0; kk_ < 2; ++kk_)                         \
  _Pragma("unroll") for (int m_ = 0; m_ < 4; ++m_)                            \
  _Pragma("unroll") for (int n_ = 0; n_ < 3; ++n_)                            \
    acc[(MQ)*4 + m_][n_] = __builtin_amdgcn_mfma_f32_16x16x32_bf16(           \
        a[kk_][m_], b[kk_][n_], acc[(MQ)*4 + m_][n_], 0, 0, 0);               \
  __builtin_amdgcn_s_setprio(0);

__global__ __launch_bounds__(512, 2)
void gemm192_bt(const ushort_t* __restrict__ A, const ushort_t* __restrict__ Bt,
                const float* __restrict__ bias, ushort_t* __restrict__ Cout,
                int M, int N, int K, int nbn) {
    __shared__ char sm[114688];
    const int tid = threadIdx.x;
    const int lane = tid & 63;
    const int w = tid >> 6;                 // 0..7
    const int wm = w >> 2, wn = w & 3;      // 2M x 4N waves
    const int r = lane & 15, hi = lane >> 4;

    const int cpx = gridDim.x >> 3;
    const int bid = blockIdx.x;
    const int x = (bid & 7) * cpx + (bid >> 3);
    const int bm = x / nbn, bn = x % nbn;
    const int m0 = bm * 256, n0 = bn * 192;

    const int NT = K >> 6;                  // 16 K-tiles
    const int NI = NT >> 1;                 // 8 iterations

    char* const A0 = sm;
    char* const B0 = sm + 32768;
    char* const A1 = sm + 57344;
    char* const B1 = sm + 90112;

    int offA[2][4], offB[2][3];
#pragma unroll
    for (int kk = 0; kk < 2; ++kk) {
#pragma unroll
        for (int m = 0; m < 4; ++m) {
            int rowL = wm * 128 + m * 16 + r;
            offA[kk][m] = rowL * 128 + (((kk * 4 + hi) ^ (rowL & 7)) * 16);
        }
#pragma unroll
        for (int n = 0; n < 3; ++n) {
            int rowL = wn * 48 + n * 16 + r;
            offB[kk][n] = rowL * 128 + (((kk * 4 + hi) ^ (rowL & 7)) * 16);
        }
    }

    f32x4 acc[8][3];
#pragma unroll
    for (int am = 0; am < 8; ++am)
#pragma unroll
        for (int an = 0; an < 3; ++an) acc[am][an] = (f32x4){0.f, 0.f, 0.f, 0.f};

    bf16x8 a[2][4], b[2][3];

    STAGE_U(A,  K, m0,        0, A0);
    STAGE_U(A,  K, m0 + 64,   0, A0 + 8192);
    STAGE_U(A,  K, m0 + 128,  0, A0 + 16384);
    STAGE_U(A,  K, m0 + 192,  0, A0 + 24576);
    STAGE_U(Bt, K, n0,        0, B0);
    STAGE_U(Bt, K, n0 + 64,   0, B0 + 8192);
    STAGE_U(Bt, K, n0 + 128,  0, B0 + 16384);
    STAGE_U(A,  K, m0,       64, A1);
    STAGE_U(A,  K, m0 + 128, 64, A1 + 16384);
    asm volatile("s_waitcnt vmcnt(2)" ::: "memory");
    __builtin_amdgcn_s_barrier();

    for (int i = 0; i < NI; ++i) {
        const int k1 = (2 * i + 1) * 64;
        const int k2 = ((2 * i + 2) % NT) * 64;
        const int k3 = ((2 * i + 3) % NT) * 64;

        STAGE_U(A,  K, m0 + 64,  k1, A1 + 8192);
        STAGE_U(A,  K, m0 + 192, k1, A1 + 24576);
        STAGE_U(Bt, K, n0,       k1, B1);
        STAGE_U(Bt, K, n0 + 64,  k1, B1 + 8192);
        STAGE_U(Bt, K, n0 + 128, k1, B1 + 16384);
        DS_A192(A0, 0); DS_B192(B0);
        BAR_LGKM; MFMA_Q(0);
        __builtin_amdgcn_s_barrier();

        STAGE_U(A, K, m0,       k2, A0);
        STAGE_U(A, K, m0 + 128, k2, A0 + 16384);
        DS_A192(A0, 8192);
        BAR_LGKM; MFMA_Q(1);
        asm volatile("s_waitcnt vmcnt(2)" ::: "memory");
        __builtin_amdgcn_s_barrier();

        STAGE_U(A,  K, m0 + 64,  k2, A0 + 8192);
        STAGE_U(A,  K, m0 + 192, k2, A0 + 24576);
        STAGE_U(Bt, K, n0,       k2, B0);
        STAGE_U(Bt, K, n0 + 64,  k2, B0 + 8192);
        STAGE_U(Bt, K, n0 + 128, k2, B0 + 16384);
        DS_A192(A1, 0); DS_B192(B1);
        BAR_LGKM; MFMA_Q(0);
        __builtin_amdgcn_s_barrier();

        STAGE_U(A, K, m0,       k3, A1);
        STAGE_U(A, K, m0 + 128, k3, A1 + 16384);
        DS_A192(A1, 8192);
        BAR_LGKM; MFMA_Q(1);
        asm volatile("s_waitcnt vmcnt(2)" ::: "memory");
        __builtin_amdgcn_s_barrier();
    }

#pragma unroll
    for (int am = 0; am < 8; ++am) {
        int rowg = m0 + wm * 128 + (am >> 2) * 64 + (am & 3) * 16 + hi * 4;
#pragma unroll
        for (int an = 0; an < 3; ++an) {
            int colg = n0 + wn * 48 + an * 16 + r;
            float bv = bias[colg];
#pragma unroll
            for (int j = 0; j < 4; ++j) {
                float v = acc[am][an][j] + bv;
                Cout[(size_t)(rowg + j) * N + colg] = f2bf(v);
            }
        }
    }
}

// =====================================================================
// GEMM2: 128x128 tile, 4-phase counted-vmcnt port. 512 threads, 8 waves
// (2M x 4N), per-wave 64x32, BK=64. Grid 32x8 = 256 blocks = 1/CU.
// Ledger: prologue {T0.A,T0.B,T1.B} vmcnt(2); ph2/ph4 vmcnt(2); B held
// in regs across the mq pair so its LDS region frees after ph1/ph3.
// =====================================================================

#define G2_DSA(BASE, MQ)                                                      \
  _Pragma("unroll") for (int kk_ = 0; kk_ < 2; ++kk_)                         \
  _Pragma("unroll") for (int m_ = 0; m_ < 2; ++m_)                            \
    a2[kk_][m_] = *reinterpret_cast<const bf16x8*>((BASE) + offA2[kk_][(MQ)*2 + m_]);

#define G2_DSB(BASE)                                                          \
  _Pragma("unroll") for (int kk_ = 0; kk_ < 2; ++kk_)                         \
  _Pragma("unroll") for (int n_ = 0; n_ < 2; ++n_)                            \
    b2[kk_][n_] = *reinterpret_cast<const bf16x8*>((BASE) + offB2[kk_][n_]);

#define G2_MFMA(MQ)                                                           \
  __builtin_amdgcn_s_setprio(1);                                              \
  _Pragma("unroll") for (int kk_ = 0; kk_ < 2; ++kk_)                         \
  _Pragma("unroll") for (int m_ = 0; m_ < 2; ++m_)                            \
  _Pragma("unroll") for (int n_ = 0; n_ < 2; ++n_)                            \
    acc[(MQ)*2 + m_][n_] = __builtin_amdgcn_mfma_f32_16x16x32_bf16(           \
        a2[kk_][m_], b2[kk_][n_], acc[(MQ)*2 + m_][n_], 0, 0, 0);             \
  __builtin_amdgcn_s_setprio(0);

__global__ __launch_bounds__(512, 2)
void gemm128_4ph(const ushort_t* __restrict__ A, const ushort_t* __restrict__ Bt,
                 const float* __restrict__ bias, float* __restrict__ Cout,
                 int M, int N, int K, int nbn) {
    __shared__ char sm[65536];
    const int tid = threadIdx.x;
    const int lane = tid & 63;
    const int w = tid >> 6;
    const int wm = w >> 2, wn = w & 3;      // 2M x 4N
    const int r = lane & 15, hi = lane >> 4;

    const int cpx = gridDim.x >> 3;
    const int bid = blockIdx.x;
    const int x = (bid & 7) * cpx + (bid >> 3);
    const int bm = x / nbn, bn = x % nbn;
    const int m0 = bm * 128, n0 = bn * 128;

    const int NT = K >> 6;                  // 16
    const int NI = NT >> 1;                 // 8

    char* const A0 = sm;                    // 16KB (2 units)
    char* const B0 = sm + 16384;
    char* const A1 = sm + 32768;
    char* const B1 = sm + 49152;

    int offA2[2][4], offB2[2][2];
#pragma unroll
    for (int kk = 0; kk < 2; ++kk) {
#pragma unroll
        for (int m = 0; m < 4; ++m) {
            int rowL = wm * 64 + m * 16 + r;
            offA2[kk][m] = rowL * 128 + (((kk * 4 + hi) ^ (rowL & 7)) * 16);
        }
#pragma unroll
        for (int n = 0; n < 2; ++n) {
            int rowL = wn * 32 + n * 16 + r;
            offB2[kk][n] = rowL * 128 + (((kk * 4 + hi) ^ (rowL & 7)) * 16);
        }
    }

    f32x4 acc[4][2];
#pragma unroll
    for (int am = 0; am < 4; ++am)
#pragma unroll
        for (int an = 0; an < 2; ++an) acc[am][an] = (f32x4){0.f, 0.f, 0.f, 0.f};

    bf16x8 a2[2][2], b2[2][2];

    // prologue: T0.A, T0.B, T1.B ; keep T1.B in flight
    STAGE_U(A,  K, m0,       0, A0);
    STAGE_U(A,  K, m0 + 64,  0, A0 + 8192);
    STAGE_U(Bt, K, n0,       0, B0);
    STAGE_U(Bt, K, n0 + 64,  0, B0 + 8192);
    STAGE_U(Bt, K, n0,      64, B1);
    STAGE_U(Bt, K, n0 + 64, 64, B1 + 8192);
    asm volatile("s_waitcnt vmcnt(2)" ::: "memory");
    __builtin_amdgcn_s_barrier();

    for (int i = 0; i < NI; ++i) {
        const int k1 = (2 * i + 1) * 64;
        const int k2 = ((2 * i + 2) % NT) * 64;
        const int k3 = ((2 * i + 3) % NT) * 64;

        // ph1: stage T1.A -> buf1; compute T0 mq0 (reads A0 lower + B0)
        STAGE_U(A, K, m0,      k1, A1);
        STAGE_U(A, K, m0 + 64, k1, A1 + 8192);
        G2_DSA(A0, 0); G2_DSB(B0);
        BAR_LGKM; G2_MFMA(0);
        __builtin_amdgcn_s_barrier();

        // ph2: stage T2.B -> B0 (B0 regs held); compute T0 mq1; vmcnt(2)
        STAGE_U(Bt, K, n0,      k2, B0);
        STAGE_U(Bt, K, n0 + 64, k2, B0 + 8192);
        G2_DSA(A0, 1);
        BAR_LGKM; G2_MFMA(1);
        asm volatile("s_waitcnt vmcnt(2)" ::: "memory");
        __builtin_amdgcn_s_barrier();

        // ph3: stage T2.A -> A0; compute T1 mq0 (reads A1 + B1)
        STAGE_U(A, K, m0,      k2, A0);
        STAGE_U(A, K, m0 + 64, k2, A0 + 8192);
        G2_DSA(A1, 0); G2_DSB(B1);
        BAR_LGKM; G2_MFMA(0);
        __builtin_amdgcn_s_barrier();

        // ph4: stage T3.B -> B1; compute T1 mq1; vmcnt(2)
        STAGE_U(Bt, K, n0,      k3, B1);
        STAGE_U(Bt, K, n0 + 64, k3, B1 + 8192);
        G2_DSA(A1, 1);
        BAR_LGKM; G2_MFMA(1);
        asm volatile("s_waitcnt vmcnt(2)" ::: "memory");
        __builtin_amdgcn_s_barrier();
    }

    // epilogue: f32 out + bias
#pragma unroll
    for (int am = 0; am < 4; ++am) {
        int rowg = m0 + wm * 64 + am * 16 + hi * 4;
#pragma unroll
        for (int an = 0; an < 2; ++an) {
            int colg = n0 + wn * 32 + an * 16 + r;
            float bv = bias[colg];
#pragma unroll
            for (int j = 0; j < 4; ++j)
                Cout[(size_t)(rowg + j) * N + colg] = acc[am][an][j] + bv;
        }
    }
}

// ---------- banded attention v3 (R8, unchanged) ----------
__global__ __launch_bounds__(256, 4)
void attn_kernel(const ushort_t* __restrict__ qkv, const ushort_t* __restrict__ vt,
                 ushort_t* __restrict__ attn_out) {
    __shared__ uint4 smem4[50176 / 16];
    char* smem = (char*)smem4;

    const int bid0 = blockIdx.x;
    const int bid = (bid0 & 7) * 128 + (bid0 >> 3);   // XCD-chunked
    const int qb = bid & 31;
    const int h = (bid >> 5) & 15;
    const int b = bid >> 9;
    const int q0 = qb * 64;
    const int kstart = (q0 - 64 > 0) ? (q0 - 64) : 0;

    const int tid = threadIdx.x;
    const int lane = tid & 63;
    const int w = tid >> 6;
    const int r = lane & 15, hi = lane >> 4;

#pragma unroll
    for (int i = 0; i < 6; ++i) {
        int task = i * 256 + tid;
        int row = task >> 3, ch = task & 7;
        int key = kstart + row;
        uint4 v = make_uint4(0u, 0u, 0u, 0u);
        if (key < SQ)
            v = *reinterpret_cast<const uint4*>(
                qkv + (size_t)(b * SQ + key) * 3072 + 1024 + h * 64 + ch * 8);
        int byte = row * 128 + ch * 16; byte ^= (row & 7) << 4;
        *reinterpret_cast<uint4*>(smem + byte) = v;
    }
    {
        const ushort_t* vtb = vt + (size_t)(b * NH + h) * HD * SQ;
        int d = tid >> 2, cp = tid & 3;
#pragma unroll
        for (int i = 0; i < 6; ++i) {
            int c = cp + i * 4;
            uint4 v = make_uint4(0u, 0u, 0u, 0u);
            int k8 = kstart + c * 8;
            if (k8 < SQ)
                v = *reinterpret_cast<const uint4*>(vtb + (size_t)d * SQ + k8);
            int byte = d * 384 + (((c & 7) ^ (d & 7)) * 16) + ((c >> 3) * 128);
            *reinterpret_cast<uint4*>(smem + 25600 + byte) = v;
        }
    }

    const ushort_t* qrow = qkv + (size_t)(b * SQ + q0 + w * 16 + r) * 3072 + h * 64;
    bf16x8 aq0 = *reinterpret_cast<const bf16x8*>(qrow + hi * 8);
    bf16x8 aq1 = *reinterpret_cast<const bf16x8*>(qrow + 32 + hi * 8);

    __syncthreads();   // barrier #1

    const int delta = q0 - kstart;
    const int base = w * 16 + delta;
    int tmin = (base - 64) >> 4; if (tmin < 0) tmin = 0;
    int tmax = (base + 79) >> 4;
    int tcap = (SQ - 1 - kstart) >> 4; if (tmax > tcap) tmax = tcap;
    if (tmax > 11) tmax = 11;
    const int ksmin = tmin >> 1, ksmax = tmax >> 1;

    f32x4 acc[12];
#pragma unroll
    for (int t = 0; t < 12; ++t) acc[t] = (f32x4){0.f, 0.f, 0.f, 0.f};
#pragma unroll
    for (int t = 0; t < 12; ++t) {
        if (t < tmin || t > tmax) continue;
#pragma unroll
        for (int ks = 0; ks < 2; ++ks) {
            int row = t * 16 + r;
            int byte = row * 128 + ks * 64 + hi * 16; byte ^= (row & 7) << 4;
            bf16x8 bk = *reinterpret_cast<const bf16x8*>(smem + byte);
            acc[t] = __builtin_amdgcn_mfma_f32_16x16x32_bf16(
                ks == 0 ? aq0 : aq1, bk, acc[t], 0, 0, 0);
        }
    }

    float mrow[4], lrow[4];
#pragma unroll
    for (int t = 0; t < 12; ++t) {
        if (t < tmin || t > tmax) continue;
        int key = kstart + t * 16 + r;
#pragma unroll
        for (int j = 0; j < 4; ++j) {
            int qrow_g = q0 + w * 16 + hi * 4 + j;
            int dd = key - qrow_g; if (dd < 0) dd = -dd;
            bool valid = (key < SQ) && (dd <= 64);
            acc[t][j] = valid ? acc[t][j] * 0.125f : -1e30f;
        }
    }
#pragma unroll
    for (int j = 0; j < 4; ++j) {
        float m = -1e30f;
#pragma unroll
        for (int t = 0; t < 12; ++t) {
            if (t < tmin || t > tmax) continue;
            m = fmaxf(m, acc[t][j]);
        }
        m = fmaxf(m, __shfl_xor(m, 1));
        m = fmaxf(m, __shfl_xor(m, 2));
        m = fmaxf(m, __shfl_xor(m, 4));
        m = fmaxf(m, __shfl_xor(m, 8));
        mrow[j] = m;
    }
#pragma unroll
    for (int j = 0; j < 4; ++j) {
        float s = 0.f;
#pragma unroll
        for (int t = 0; t < 12; ++t) {
            if (t < tmin || t > tmax) continue;
            float p = __expf(acc[t][j] - mrow[j]);
            acc[t][j] = p;
            s += p;
        }
        s += __shfl_xor(s, 1);
        s += __shfl_xor(s, 2);
        s += __shfl_xor(s, 4);
        s += __shfl_xor(s, 8);
        lrow[j] = s;
    }

    __syncthreads();   // barrier #2

#pragma unroll
    for (int t = 0; t < 12; ++t) {
        int col = t * 16 + r;
        bool inb = (t >= tmin) && (t <= tmax);
#pragma unroll
        for (int j = 0; j < 4; ++j) {
            int rowL = w * 16 + hi * 4 + j;
            ushort_t pv = inb ? f2bf(acc[t][j]) : (ushort_t)0;
            *reinterpret_cast<ushort_t*>(smem + rowL * 400 + col * 2) = pv;
        }
    }

    f32x4 oacc[4];
#pragma unroll
    for (int dt = 0; dt < 4; ++dt) oacc[dt] = (f32x4){0.f, 0.f, 0.f, 0.f};
#pragma unroll
    for (int ks = 0; ks < 6; ++ks) {
        if (ks < ksmin || ks > ksmax) continue;
        int k0 = ks * 32 + hi * 8;
        bf16x8 ap = *reinterpret_cast<const bf16x8*>(
            smem + (w * 16 + r) * 400 + k0 * 2);
        int cch = ks * 4 + hi;
#pragma unroll
        for (int dt = 0; dt < 4; ++dt) {
            int d = dt * 16 + r;
            int byte = d * 384 + (((cch & 7) ^ (d & 7)) * 16) + ((cch >> 3) * 128);
            bf16x8 bv = *reinterpret_cast<const bf16x8*>(smem + 25600 + byte);
            oacc[dt] = __builtin_amdgcn_mfma_f32_16x16x32_bf16(ap, bv, oacc[dt], 0, 0, 0);
        }
    }

    float inv[4];
#pragma unroll
    for (int j = 0; j < 4; ++j) inv[j] = 1.0f / lrow[j];
#pragma unroll
    for (int dt = 0; dt < 4; ++dt) {
        int d = dt * 16 + r;
#pragma unroll
        for (int j = 0; j < 4; ++j) {
            int q = q0 + w * 16 + hi * 4 + j;
            attn_out[(size_t)(b * SQ + q) * 1024 + h * 64 + d] = f2bf(oacc[dt][j] * inv[j]);
        }
    }
}

// ---------- launch ----------
extern "C" void kernel_launch(void* const* d_in, const int* in_sizes, int n_in,
                              void* d_out, int out_size, void* d_ws, size_t ws_size,
                              hipStream_t stream) {
    const float* x     = (const float*)d_in[0];
    const float* w_qkv = (const float*)d_in[1];
    const float* b_qkv = (const float*)d_in[2];
    const float* w_out = (const float*)d_in[3];
    const float* b_out = (const float*)d_in[4];
    float* out = (float*)d_out;

    char* ws = (char*)d_ws;
    ushort_t* xb    = (ushort_t*)(ws);                       // 8 MB  [4096][1024]
    ushort_t* wqkvT = (ushort_t*)(ws + 8388608);             // 6 MB  [3072][1024]
    ushort_t* woutT = (ushort_t*)(ws + 14680064);            // 2 MB  [1024][1024]
    ushort_t* qkv   = (ushort_t*)(ws + 16777216);            // 24 MB [4096][3072]
    ushort_t* aout  = (ushort_t*)(ws + 41943040);            // 8 MB  [4096][1024]
    ushort_t* vtbuf = (ushort_t*)(ws + 50331648);            // 8 MB  [32][64][2048]

    prep_kernel<<<5120, 256, 0, stream>>>(x, xb, w_qkv, wqkvT, w_out, woutT);

    gemm192_bt<<<256, 512, 0, stream>>>(xb, wqkvT, b_qkv, qkv, 4096, 3072, 1024, 16);
    transpose_v<<<dim3(64, 2, 32), dim3(32, 8), 0, stream>>>(qkv, vtbuf);
    attn_kernel<<<1024, 256, 0, stream>>>(qkv, vtbuf, aout);
    // GEMM2: 4096x1024x1024, 128x128 tiles -> grid 32*8 = 256 = 1 block/CU
    gemm128_4ph<<<256, 512, 0, stream>>>(aout, woutT, b_out, out, 4096, 1024, 1024, 8);
}